// Round 10
// baseline (273.828 us; speedup 1.0000x reference)
//
#include <hip/hip_runtime.h>
#include <hip/hip_bf16.h>

typedef __attribute__((ext_vector_type(8))) short bf16x8;
typedef __attribute__((ext_vector_type(4))) short bf16x4;
typedef __attribute__((ext_vector_type(4))) float f32x4;
typedef __attribute__((ext_vector_type(16))) float f32x16;
typedef __attribute__((ext_vector_type(4))) int   i32x4;
typedef __attribute__((ext_vector_type(2))) unsigned u32x2;
typedef __attribute__((ext_vector_type(4))) unsigned u32x4;

#define D_MODEL 2048
#define NTOK    4096   // B*S
#define NH      16
#define HD      128
#define SEQ     2048
#define NQKV    6144   // 3*D_MODEL (concatenated q,k,v outputs)

__device__ __forceinline__ short f2bf(float f) {
  unsigned u = __builtin_bit_cast(unsigned, f);
  unsigned r = u + 0x7FFFu + ((u >> 16) & 1u);   // RNE
  return (short)(r >> 16);
}
__device__ __forceinline__ float bf2f(short s) {
  return __builtin_bit_cast(float, ((unsigned)(unsigned short)s) << 16);
}

__device__ __forceinline__ float exp2fast(float x) {
#if __has_builtin(__builtin_amdgcn_exp2f)
  return __builtin_amdgcn_exp2f(x);
#else
  return exp2f(x);
#endif
}

// pack 2 fp32 -> 2 bf16 (RNE) in one instr
__device__ __forceinline__ unsigned cvt_pk_bf16(float a, float b) {
  unsigned r;
  asm("v_cvt_pk_bf16_f32 %0, %1, %2" : "=v"(r) : "v"(a), "v"(b));
  return r;
}

// exchange: x.hi-lanes <-> y.lo-lanes. After: x = {x.lo, y.lo}, y = {x.hi, y.hi}
__device__ __forceinline__ void permswap(unsigned& x, unsigned& y) {
#if __has_builtin(__builtin_amdgcn_permlane32_swap)
  u32x2 r = __builtin_amdgcn_permlane32_swap(x, y, false, false);
  x = r[0]; y = r[1];
#else
  asm volatile("v_permlane32_swap_b32 %0, %1" : "+v"(x), "+v"(y));
#endif
}

__device__ __forceinline__ f32x16 mfma32(bf16x8 a, bf16x8 b, f32x16 c) {
  return __builtin_amdgcn_mfma_f32_32x32x16_bf16(a, b, c, 0, 0, 0);
}

// async global->LDS, 16B per lane. LDS dst must be wave-uniform; HW writes lane i at dst + i*16.
__device__ __forceinline__ void gload_lds16(const void* g, void* l) {
  typedef __attribute__((address_space(1))) const unsigned gu32;
  typedef __attribute__((address_space(3))) unsigned lu32;
  __builtin_amdgcn_global_load_lds((gu32*)(uintptr_t)g,
                                   (lu32*)(unsigned)(uintptr_t)l, 16, 0, 0);
}

// ---------------- 1. fp32 -> bf16 cast (vectorized) ----------------
__global__ __launch_bounds__(256) void cast_bf16(const float* __restrict__ in,
                                                 short* __restrict__ out, int n4) {
  int i = blockIdx.x * 256 + threadIdx.x;
  if (i >= n4) return;
  float4 v = ((const float4*)in)[i];
  short4 o;
  o.x = f2bf(v.x); o.y = f2bf(v.y); o.z = f2bf(v.z); o.w = f2bf(v.w);
  ((short4*)out)[i] = o;
}

// ---------------- 2. W (KxN) -> W^T (NxK) bf16, LDS-tiled ----------------
__global__ __launch_bounds__(256) void wtrans(const float* __restrict__ w0,
                                              const float* __restrict__ w1,
                                              const float* __restrict__ w2,
                                              const float* __restrict__ w3,
                                              short* __restrict__ wt) {
  int z = blockIdx.z;
  const float* W = (z == 0) ? w0 : (z == 1) ? w1 : (z == 2) ? w2 : w3;
  short* O = wt + (size_t)z * D_MODEL * D_MODEL;
  int n0 = blockIdx.x * 64, k0 = blockIdx.y * 64;
  __shared__ short T[64 * 136];
  int tid = threadIdx.x;
#pragma unroll
  for (int it = 0; it < 4; ++it) {
    int f = it * 256 + tid, kk = f >> 4, nc = f & 15;
    float4 v = *(const float4*)&W[(size_t)(k0 + kk) * D_MODEL + n0 + nc * 4];
    short4 o;
    o.x = f2bf(v.x); o.y = f2bf(v.y); o.z = f2bf(v.z); o.w = f2bf(v.w);
    *(short4*)&T[kk * 136 + nc * 4] = o;
  }
  __syncthreads();
#pragma unroll
  for (int it = 0; it < 4; ++it) {
    int u = it * 256 + tid, nn = u >> 4, kc = u & 15;
    short4 o;
    o.x = T[(kc * 4 + 0) * 136 + nn];
    o.y = T[(kc * 4 + 1) * 136 + nn];
    o.z = T[(kc * 4 + 2) * 136 + nn];
    o.w = T[(kc * 4 + 3) * 136 + nn];
    *(short4*)&O[(size_t)(n0 + nn) * D_MODEL + k0 + kc * 4] = o;
  }
}

// ---------------- 3/7. GEMM: 256x128 tile, BK=64, 8-phase schedule (m201 port) ----------------
// 8 waves (4m x 2n), wave tile 64x64. 3 LDS buffers x 48KB (A 32KB + B 16KB) = 144KB.
// Per K-tile: 2 phases, each {8 ds_read_b128 | 3 gload_lds(tile kt+2) | barrier | lgkmcnt(0) |
// 16 MFMA (setprio)} ; vmcnt(6) once per K-tile (end of phase 1) -> tile kt+1 landed, kt+2 in
// flight. Drain vmcnt(0) only at the 2-iter tail. Swizzle o ^= ((o>>7)&7)<<4 on both sides.
template <bool OUTBF16>
__global__ __launch_bounds__(512, 2) void gemm8p(const short* __restrict__ A,
                                                 const short* __restrict__ Bt,
                                                 void* __restrict__ Cv, int CS) {
  __shared__ char L[3 * 49152];   // 147456 B
  int tid = threadIdx.x, w = tid >> 6, lane = tid & 63, c = lane & 15, g = lane >> 4;

  // supertile(4x4) + XCD-chunk block swizzle (requires gx%4==0, gy%4==0, (gx*gy)%128==0)
  int gx = gridDim.x, gy = gridDim.y;
  int lin = blockIdx.x + gx * blockIdx.y;
  int idx = lin >> 3, nst = (gx * gy) >> 7;
  int s = (lin & 7) * nst + (idx >> 4);
  int w16 = idx & 15;
  int smR = gy >> 2;
  int mblk = (s % smR) * 4 + (w16 >> 2);
  int nblk = (s / smR) * 4 + (w16 & 3);
  int m0 = mblk * 256, n0 = nblk * 128;
  int wm = w >> 1, wn = w & 1;

  const int NKT = D_MODEL / 64;   // 32 K-tiles

  // staging: 48KB/K-tile = 48 wave-chunks of 1KB; wave w stages 6 (3 per phase).
  // chunk ch: ch<32 -> A region (byte ch*1024), ch>=32 -> B region (byte ch*1024 = 32768+...).
  const short* gsrc[6];
  int ldst[6];
#pragma unroll
  for (int j = 0; j < 6; ++j) {
    int ch = (j / 3) * 24 + w * 3 + (j % 3);
    int o = (ch < 32 ? ch * 1024 : (ch - 32) * 1024) + lane * 16;  // region-local byte
    int r = o >> 7, colb = o & 127;                                // 128B rows (64 bf16)
    int sw = (colb ^ ((r & 7) << 4)) >> 1;                         // pre-swizzled col (elems)
    gsrc[j] = (ch < 32) ? A + (size_t)(m0 + r) * D_MODEL + sw
                        : Bt + (size_t)(n0 + r) * D_MODEL + sw;
    ldst[j] = ch * 1024;
  }

  // fragment read byte offsets per k-slice (swizzled), loop-invariant
  int aoff[2][4], boff[2][4];
#pragma unroll
  for (int ks = 0; ks < 2; ++ks) {
#pragma unroll
    for (int mi = 0; mi < 4; ++mi) {
      int r = wm * 64 + mi * 16 + c;
      aoff[ks][mi] = r * 128 + ((ks * 64 + g * 16) ^ ((r & 7) << 4));
    }
#pragma unroll
    for (int ni = 0; ni < 4; ++ni) {
      int r = wn * 64 + ni * 16 + c;
      boff[ks][ni] = 32768 + r * 128 + ((ks * 64 + g * 16) ^ ((r & 7) << 4));
    }
  }

  f32x4 acc[4][4] = {};

  // prologue: stage tiles 0 and 1 fully (12 gloads/wave in flight)
#pragma unroll
  for (int j = 0; j < 6; ++j) gload_lds16(gsrc[j], L + ldst[j]);
#pragma unroll
  for (int j = 0; j < 6; ++j) gload_lds16(gsrc[j] + 64, L + 49152 + ldst[j]);
  asm volatile("s_waitcnt vmcnt(6)" ::: "memory");   // tile 0 landed
  __builtin_amdgcn_s_barrier();

  for (int kt = 0; kt < NKT; ++kt) {
    const char* buf = L + (kt % 3) * 49152;
    char* sbase = L + ((kt + 2) % 3) * 49152;
    int skk = (kt + 2) * 64;
    bool dostage = (kt + 2 < NKT);
#pragma unroll
    for (int ph = 0; ph < 2; ++ph) {
      bf16x8 af[4], bfv[4];
#pragma unroll
      for (int mi = 0; mi < 4; ++mi) af[mi] = *(const bf16x8*)(buf + aoff[ph][mi]);
#pragma unroll
      for (int ni = 0; ni < 4; ++ni) bfv[ni] = *(const bf16x8*)(buf + boff[ph][ni]);
      if (dostage) {
#pragma unroll
        for (int j = ph * 3; j < ph * 3 + 3; ++j)
          gload_lds16(gsrc[j] + skk, sbase + ldst[j]);
      }
      __builtin_amdgcn_sched_barrier(0);
      __builtin_amdgcn_s_barrier();
      asm volatile("s_waitcnt lgkmcnt(0)" ::: "memory");
      __builtin_amdgcn_sched_barrier(0);
      __builtin_amdgcn_s_setprio(1);
#pragma unroll
      for (int mi = 0; mi < 4; ++mi)
#pragma unroll
        for (int ni = 0; ni < 4; ++ni)
          acc[mi][ni] = __builtin_amdgcn_mfma_f32_16x16x32_bf16(af[mi], bfv[ni],
                                                                acc[mi][ni], 0, 0, 0);
      __builtin_amdgcn_s_setprio(0);
      if (ph == 1) {
        if (kt + 2 < NKT)      { asm volatile("s_waitcnt vmcnt(6)" ::: "memory"); }
        else if (kt + 1 < NKT) { asm volatile("s_waitcnt vmcnt(0)" ::: "memory"); }
      }
      __builtin_amdgcn_s_barrier();
    }
  }

  int row0 = m0 + wm * 64, col0 = n0 + wn * 64;
  if (OUTBF16) {
    short* Cb = (short*)Cv;
#pragma unroll
    for (int mi = 0; mi < 4; ++mi)
#pragma unroll
      for (int ni = 0; ni < 4; ++ni)
#pragma unroll
        for (int i = 0; i < 4; ++i)
          Cb[(size_t)(row0 + mi * 16 + g * 4 + i) * CS + col0 + ni * 16 + c] =
              f2bf(acc[mi][ni][i]);
  } else {
    float* Cf = (float*)Cv;
#pragma unroll
    for (int mi = 0; mi < 4; ++mi)
#pragma unroll
      for (int ni = 0; ni < 4; ++ni)
#pragma unroll
        for (int i = 0; i < 4; ++i)
          Cf[(size_t)(row0 + mi * 16 + g * 4 + i) * CS + col0 + ni * 16 + c] =
              acc[mi][ni][i];
  }
}

// ---------------- 4. fused RMSNorm + RoPE (q,k), one wave per (token,head) ----------------
__global__ __launch_bounds__(256) void norm_rope(const short* __restrict__ qkv16,
                                                 const float* __restrict__ cosb,
                                                 const float* __restrict__ sinb,
                                                 const float* __restrict__ gq,
                                                 const float* __restrict__ gk,
                                                 short* __restrict__ qn,
                                                 short* __restrict__ kn) {
  int z = blockIdx.y;  // 0=q, 1=k
  const float* gg = z ? gk : gq;
  short* O = z ? kn : qn;
  int w = threadIdx.x >> 6, lane = threadIdx.x & 63;
  int p = blockIdx.x * 4 + w;          // (token,head) pair
  int token = p >> 4, h = p & 15;
  int v = *(const int*)&qkv16[(size_t)token * NQKV + z * D_MODEL + h * HD + lane * 2];
  float x0 = bf2f((short)(v & 0xffff));
  float x1 = bf2f((short)((unsigned)v >> 16));
  float ss = x0 * x0 + x1 * x1;
#pragma unroll
  for (int mk = 32; mk; mk >>= 1) ss += __shfl_xor(ss, mk);
  float rs = rsqrtf(ss * (1.f / 128.f) + 1e-5f);
  float qs = z ? 1.0f : 0.12751744f;   // 1/sqrt(128) * log2(e) for Q only
  rs *= qs;
  float xr = x0 * rs * gg[lane * 2];
  float xi = x1 * rs * gg[lane * 2 + 1];
  float cc = cosb[(size_t)token * 64 + lane];
  float sn = sinb[(size_t)token * 64 + lane];
  float or_ = xr * cc - xi * sn;
  float oi_ = xr * sn + xi * cc;
  int b = token >> 11, sidx = token & 2047;
  size_t dst = ((size_t)(b * NH + h) * SEQ + sidx) * HD + lane * 2;
  unsigned pk = (unsigned)(unsigned short)f2bf(or_) |
                ((unsigned)(unsigned short)f2bf(oi_) << 16);
  *(unsigned*)&O[dst] = pk;
}

// ---------------- 5. V (from qkv16 [token][6144], v at +4096) -> V^T (B,H,128,S) ----------------
__global__ __launch_bounds__(256) void vtrans(const short* __restrict__ qkv16,
                                              short* __restrict__ vt) {
  int st = blockIdx.x, bh = blockIdx.y;
  int b = bh >> 4, h = bh & 15;
  int t0 = b * SEQ + st * 64;
  __shared__ short Lt[64 * 136];
  int tid = threadIdx.x;
#pragma unroll
  for (int it = 0; it < 4; ++it) {
    int f = it * 256 + tid, tk = f >> 4, ch = f & 15;
    *(i32x4*)&Lt[tk * 136 + ch * 8] =
        *(const i32x4*)&qkv16[(size_t)(t0 + tk) * NQKV + 2 * D_MODEL + h * HD + ch * 8];
  }
  __syncthreads();
#pragma unroll
  for (int it = 0; it < 4; ++it) {
    int u = it * 256 + tid, d = u >> 3, kg = u & 7;
    bf16x8 o;
#pragma unroll
    for (int j = 0; j < 8; ++j) o[j] = Lt[(kg * 8 + j) * 136 + d];
    *(bf16x8*)&vt[(size_t)(bh * HD + d) * SEQ + st * 64 + kg * 8] = o;
  }
}

// ---------------- 6. flash attention: 8 waves x 32 q-rows, 32x32x16 MFMA ----------------
__global__ __launch_bounds__(512, 2) void flash(const short* __restrict__ qn,
                                                const short* __restrict__ kn,
                                                const short* __restrict__ vt,
                                                short* __restrict__ attn) {
  __shared__ short Ks[2][64 * 128];   // 2 x 16KB, [key][d]
  __shared__ short Vs[2][128 * 64];   // 2 x 16KB, [d][key]
  int tid = threadIdx.x, w = tid >> 6, lane = tid & 63;
  int q31 = lane & 31, hi = lane >> 5;

  // XCD-aware remap: XCD (phys%8) gets 4 bh x 8 q-blocks -> K/V L2-resident per XCD
  int phys = blockIdx.x;
  int xcd = phys & 7, idx = phys >> 3;
  int bh = xcd * 4 + (idx >> 3);
  int qb = idx & 7;
  int q0 = qb * 256 + w * 32;

  const size_t base = (size_t)bh * SEQ * HD;
  const short* Kg = kn + base;
  const short* Vg = vt + base;

  // Q fragments (B-side): position (hi, j) <- Q[q0+q31][d = s*16 + hi*8 + j]
  bf16x8 qf[8];
#pragma unroll
  for (int s = 0; s < 8; ++s)
    qf[s] = *(const bf16x8*)&qn[base + (size_t)(q0 + q31) * HD + s * 16 + hi * 8];

  f32x16 acc[4] = {};
  float m_ = -1e30f, l_ = 0.f;

  // staging source offsets (same swizzle as reads)
  int ksrc[2], vsrc[2];
#pragma unroll
  for (int p = 0; p < 2; ++p) {
    int ch = w * 2 + p;
    int o = ch * 1024 + lane * 16;
    int kr = o >> 8, kc = o & 255;                   // K: 256B rows
    ksrc[p] = kr * HD + ((kc ^ ((kr & 7) << 4)) >> 1);
    int vr = o >> 7, vc = o & 127;                   // V: 128B rows
    vsrc[p] = vr * SEQ + ((vc ^ ((vr & 7) << 4)) >> 1);
  }
  // read offsets (bytes), loop-invariant; row&7 == q31&7 for all rows used
  int swz = (q31 & 7) << 4;
  int koff[8], voff[4];
#pragma unroll
  for (int kf = 0; kf < 8; ++kf) koff[kf] = (kf * 32 + hi * 16) ^ swz;
#pragma unroll
  for (int kk = 0; kk < 4; ++kk) voff[kk] = (kk * 32 + hi * 16) ^ swz;
  int krow0 = q31 * 256, krow1 = (32 + q31) * 256;

  // prologue: stage tile 0 into buffer 0
#pragma unroll
  for (int p = 0; p < 2; ++p) {
    int ch = w * 2 + p;
    gload_lds16(Kg + ksrc[p], (char*)&Ks[0][0] + ch * 1024);
    gload_lds16(Vg + vsrc[p], (char*)&Vs[0][0] + ch * 1024);
  }

  const int NT = SEQ / 64;
  for (int t = 0; t < NT; ++t) {
    int cur = t & 1;
    __syncthreads();           // vmcnt(0) drain => buf[cur] ready; buf[cur^1] free
    if (t + 1 < NT) {
      int k0n = (t + 1) * 64;
#pragma unroll
      for (int p = 0; p < 2; ++p) {
        int ch = w * 2 + p;
        gload_lds16(Kg + (size_t)k0n * HD + ksrc[p], (char*)&Ks[cur ^ 1][0] + ch * 1024);
        gload_lds16(Vg + k0n + vsrc[p],              (char*)&Vs[cur ^ 1][0] + ch * 1024);
      }
    }
    const char* Kb = (const char*)&Ks[cur][0];
    const char* Vb = (const char*)&Vs[cur][0];

    // QK^T: two 32x32 blocks (keys 0-31, 32-63), K=128 over 8 slices
    f32x16 s0 = {0,0,0,0,0,0,0,0,0,0,0,0,0,0,0,0};
    f32x16 s1 = {0,0,0,0,0,0,0,0,0,0,0,0,0,0,0,0};
    __builtin_amdgcn_s_setprio(1);
#pragma unroll
    for (int kf = 0; kf < 8; ++kf) {
      bf16x8 k0 = *(const bf16x8*)(Kb + krow0 + koff[kf]);
      s0 = mfma32(k0, qf[kf], s0);
      bf16x8 k1 = *(const bf16x8*)(Kb + krow1 + koff[kf]);
      s1 = mfma32(k1, qf[kf], s1);
    }
    __builtin_amdgcn_s_setprio(0);

    // per-lane scalar online softmax (q = q31); halves hold disjoint k's of same q
    float p0 = -1e30f, p1 = -1e30f, p2 = -1e30f, p3 = -1e30f;
#pragma unroll
    for (int i = 0; i < 4; ++i) {
      p0 = fmaxf(p0, fmaxf(s0[i], s0[i + 4]));
      p1 = fmaxf(p1, fmaxf(s0[i + 8], s0[i + 12]));
      p2 = fmaxf(p2, fmaxf(s1[i], s1[i + 4]));
      p3 = fmaxf(p3, fmaxf(s1[i + 8], s1[i + 12]));
    }
    float pmax = fmaxf(fmaxf(p0, p1), fmaxf(p2, p3));
    pmax = fmaxf(pmax, __shfl_xor(pmax, 32));
    if (!__all(pmax <= m_ + 11.5f)) {   // defer-max: p bounded by 2^11.5
      float mn = fmaxf(m_, pmax);
      float al = exp2fast(m_ - mn);
      m_ = mn; l_ *= al;
#pragma unroll
      for (int db = 0; db < 4; ++db)
#pragma unroll
        for (int i = 0; i < 16; ++i) acc[db][i] *= al;
    }
    float r0 = 0.f, r1 = 0.f;
#pragma unroll
    for (int i = 0; i < 16; ++i) {
      float pa = exp2fast(s0[i] - m_); r0 += pa; s0[i] = pa;
      float pb = exp2fast(s1[i] - m_); r1 += pb; s1[i] = pb;
    }
    float r = r0 + r1;
    r += __shfl_xor(r, 32);
    l_ += r;

    // pack P -> B-frags and PV (cvt_pk + permlane32_swap)
    __builtin_amdgcn_s_setprio(1);
#pragma unroll
    for (int kt = 0; kt < 2; ++kt) {
      const f32x16& sv = kt ? s1 : s0;
#pragma unroll
      for (int c2 = 0; c2 < 2; ++c2) {
        unsigned x0 = cvt_pk_bf16(sv[c2 * 8 + 0], sv[c2 * 8 + 1]);
        unsigned x1 = cvt_pk_bf16(sv[c2 * 8 + 2], sv[c2 * 8 + 3]);
        unsigned y0 = cvt_pk_bf16(sv[c2 * 8 + 4], sv[c2 * 8 + 5]);
        unsigned y1 = cvt_pk_bf16(sv[c2 * 8 + 6], sv[c2 * 8 + 7]);
        permswap(x0, y0);
        permswap(x1, y1);
        u32x4 pw = {x0, x1, y0, y1};
        bf16x8 pfrag = __builtin_bit_cast(bf16x8, pw);
        int vo = voff[kt * 2 + c2];
#pragma unroll
        for (int db = 0; db < 4; ++db) {
          bf16x8 va = *(const bf16x8*)(Vb + (db * 32 + q31) * 128 + vo);
          acc[db] = mfma32(va, pfrag, acc[db]);
        }
      }
    }
    __builtin_amdgcn_s_setprio(0);
  }

  int b = bh >> 4, h = bh & 15;
  float linv = 1.f / l_;
  size_t orow = (size_t)(b * SEQ + q0 + q31) * D_MODEL + h * HD;
#pragma unroll
  for (int db = 0; db < 4; ++db)
#pragma unroll
    for (int rg = 0; rg < 4; ++rg) {
      short4 o;
      o.x = f2bf(acc[db][rg * 4 + 0] * linv);
      o.y = f2bf(acc[db][rg * 4 + 1] * linv);
      o.z = f2bf(acc[db][rg * 4 + 2] * linv);
      o.w = f2bf(acc[db][rg * 4 + 3] * linv);
      *(short4*)&attn[orow + db * 32 + rg * 8 + hi * 4] = o;
    }
}

// ---------------- launch ----------------
extern "C" void kernel_launch(void* const* d_in, const int* in_sizes, int n_in,
                              void* d_out, int out_size, void* d_ws, size_t ws_size,
                              hipStream_t stream) {
  const float* hs   = (const float*)d_in[0];
  const float* fcos = (const float*)d_in[1];
  const float* fsin = (const float*)d_in[2];
  const float* Wq   = (const float*)d_in[3];
  const float* Wk   = (const float*)d_in[4];
  const float* Wv   = (const float*)d_in[5];
  const float* Wo   = (const float*)d_in[6];
  const float* gq   = (const float*)d_in[7];
  const float* gk   = (const float*)d_in[8];

  char* ws = (char*)d_ws;
  short* hs16  = (short*)ws;                        // 16,777,216 B (reused as attn16 later)
  short* Wt    = (short*)(ws + 16777216);           // 33,554,432 B ([Wq|Wk|Wv|Wo] N-major)
  short* qkv16 = (short*)(ws + 50331648);           // 50,331,648 B ([token][6144])
  short* qn    = (short*)(ws + 100663296);          // 16,777,216 B (B,H,S,128)
  short* kn    = (short*)(ws + 117440512);          // 16,777,216 B
  short* vt    = (short*)(ws + 134217728);          // 16,777,216 B (B,H,128,S)
  short* attn16 = hs16;  // hs16 dead after QKV GEMM

  cast_bf16<<<8192, 256, 0, stream>>>(hs, hs16, NTOK * D_MODEL / 4);
  wtrans<<<dim3(32, 32, 4), 256, 0, stream>>>(Wq, Wk, Wv, Wo, Wt);
  // QKV: M=4096 x N=6144, grid 48x16 = 768 blocks = 3 full CU-rounds at 1 block/CU
  gemm8p<true><<<dim3(48, 16), 512, 0, stream>>>(hs16, Wt, qkv16, NQKV);
  norm_rope<<<dim3(16384, 2), 256, 0, stream>>>(qkv16, fcos, fsin, gq, gk, qn, kn);
  vtrans<<<dim3(32, 32), 256, 0, stream>>>(qkv16, vt);
  flash<<<dim3(256), 512, 0, stream>>>(qn, kn, vt, attn16);
  // Wo: M=4096 x N=2048, grid 16x16 = 256 blocks = 1 full round
  gemm8p<false><<<dim3(16, 16), 512, 0, stream>>>(attn16,
                                                  Wt + (size_t)3 * D_MODEL * D_MODEL,
                                                  d_out, D_MODEL);
}